// Round 1
// 515.890 us; speedup vs baseline: 1.1706x; 1.1706x over previous
//
#include <hip/hip_runtime.h>
#include <math.h>

// Problem constants
#define BB 4
#define CC 64
#define C2 128
#define HH 128
#define WW 256
#define NN (BB*HH)          // 512 row-pairs
#define EPSBN 1e-5f

typedef _Float16 f16;
typedef _Float16 half8 __attribute__((ext_vector_type(8)));
typedef float f32x4 __attribute__((ext_vector_type(4)));

// ---------------------------------------------------------------------------
// K0: weight prep — rb_w fp32 [o][icg][3][3] -> f16 [g][mo][ks*32+ic]
// (MFMA-fragment order; conv blocks then read coalesced b128).  grid (4,2).
// ---------------------------------------------------------------------------
__global__ __launch_bounds__(256) void k_wprep(
    const float* __restrict__ w1, const float* __restrict__ w2,
    f16* __restrict__ wp1, f16* __restrict__ wp2)
{
    int g = blockIdx.x; int which = blockIdx.y;
    const float* src = which ? w2 : w1;
    f16* dst = which ? wp2 : wp1;
    for (int p = threadIdx.x; p < 9216; p += 256) {
        int mo = p / 288; int kr = p - mo*288;
        int ks = kr >> 5; int ic = kr & 31;
        dst[g*9216 + p] = (f16)src[((g*32 + mo)*32 + ic)*9 + ks];
    }
}

// ---------------------------------------------------------------------------
// K1: fused 1x1 conv (64->64) + concat + batchnorm -> u (channel-last f16)
// via MFMA 16x16x32 f16.  u[n][px][128].  grid 512 = (b,h); 256 thr = 4 waves.
// ---------------------------------------------------------------------------
__global__ __launch_bounds__(256) void k_catbn_m(
    const float* __restrict__ x, const float* __restrict__ cw, const float* __restrict__ cb,
    const float* __restrict__ g, const float* __restrict__ bb_, const float* __restrict__ m,
    const float* __restrict__ v, f16* __restrict__ u)
{
    __shared__ f16 Xl[256][72];   // [px][ic]
    __shared__ f16 Wl[64][72];    // [oc][ic]
    __shared__ float sS[64], sT[64], sS2[64], sT2[64];
    int n = blockIdx.x; int b = n >> 7; int h = n & 127; int t = threadIdx.x;
    for (int p = t; p < 2048; p += 256) {
        int idx = p * 2; int o = idx >> 6, i = idx & 63;
        union { f16 h[2]; unsigned int u1; } pr;
        pr.h[0] = (f16)cw[idx]; pr.h[1] = (f16)cw[idx + 1];
        *(unsigned int*)&Wl[o][i] = pr.u1;
    }
    if (t < 64) {
        float inv = rsqrtf(v[t] + EPSBN); float s = g[t] * inv;
        sS[t] = s; sT[t] = bb_[t] + s * (cb[t] - m[t]);
        float inv2 = rsqrtf(v[t + 64] + EPSBN); float s2 = g[t + 64] * inv2;
        sS2[t] = s2; sT2[t] = bb_[t + 64] - s2 * m[t + 64];
    }
    __syncthreads();
    f16* up = u + ((size_t)(n*256 + t)) * 128;
    for (int c8 = 0; c8 < 8; ++c8) {
        float xv8[8];
#pragma unroll
        for (int j = 0; j < 8; ++j)
            xv8[j] = x[(((b*64 + c8*8 + j)*128 + h) << 8) + t];
        union { f16 h[8]; uint4 v4; } pk;
#pragma unroll
        for (int j = 0; j < 8; ++j) {
            int c = c8*8 + j;
            pk.h[j] = (f16)(sS2[c]*xv8[j] + sT2[c]);
        }
        *(uint4*)(up + 64 + c8*8) = pk.v4;
#pragma unroll
        for (int j2 = 0; j2 < 4; ++j2) {
            union { f16 h[2]; unsigned int u1; } q;
            q.h[0] = (f16)xv8[j2*2]; q.h[1] = (f16)xv8[j2*2 + 1];
            *(unsigned int*)&Xl[t][c8*8 + j2*2] = q.u1;
        }
    }
    __syncthreads();
    int lane = t & 63, wv = t >> 6;
    int m16 = lane & 15, quad = lane >> 4;
    half8 af[4][2], bf[4][2];
#pragma unroll
    for (int mt = 0; mt < 4; ++mt)
#pragma unroll
        for (int kk = 0; kk < 2; ++kk)
            af[mt][kk] = *(const half8*)&Wl[mt*16 + m16][kk*32 + quad*8];
#pragma unroll
    for (int nt = 0; nt < 4; ++nt)
#pragma unroll
        for (int kk = 0; kk < 2; ++kk)
            bf[nt][kk] = *(const half8*)&Xl[wv*64 + nt*16 + m16][kk*32 + quad*8];
    f32x4 acc[4][4] = {};
#pragma unroll
    for (int mt = 0; mt < 4; ++mt)
#pragma unroll
        for (int nt = 0; nt < 4; ++nt) {
            acc[mt][nt] = __builtin_amdgcn_mfma_f32_16x16x32_f16(af[mt][0], bf[nt][0], acc[mt][nt], 0, 0, 0);
            acc[mt][nt] = __builtin_amdgcn_mfma_f32_16x16x32_f16(af[mt][1], bf[nt][1], acc[mt][nt], 0, 0, 0);
        }
#pragma unroll
    for (int mt = 0; mt < 4; ++mt) {
        int ocb = mt*16 + quad*4;
        float s4[4], t4[4];
        *(float4*)s4 = *(const float4*)&sS[ocb];
        *(float4*)t4 = *(const float4*)&sT[ocb];
#pragma unroll
        for (int nt = 0; nt < 4; ++nt) {
            int px = wv*64 + nt*16 + m16;
            union { f16 h[4]; uint2 u2; } ov;
#pragma unroll
            for (int r = 0; r < 4; ++r)
                ov.h[r] = (f16)(s4[r]*acc[mt][nt][r] + t4[r]);
            *(uint2*)(u + ((size_t)(n*256 + px))*128 + ocb) = ov.u2;
        }
    }
}

// ---------------------------------------------------------------------------
// K2/K3: grouped 3x3 conv, implicit-GEMM f16 MFMA, 4 output rows per block.
// Weights pre-transformed (k_wprep) -> loaded straight into registers.
// grid (128 = b*htile, 4 group, 2 wtile); 256 thr = 4 waves.
// Wave: 32 px x 32 oc per row, 4 rows.  LDS: 6 input rows only (62.4 KB).
// ---------------------------------------------------------------------------
template<bool LEAKY, bool RES>
__global__ __launch_bounds__(256, 2) void k_conv3r(
    const f16* __restrict__ in, const f16* __restrict__ wp,
    const float* __restrict__ bias, const f16* __restrict__ res,
    f16* __restrict__ out)
{
    __shared__ f16 Xl[6*130*40];  // [row][px][ic] px-stride 40
    int b = blockIdx.x >> 5; int h0 = (blockIdx.x & 31) * 4;
    int g = blockIdx.y; int w0 = blockIdx.z * 128;
    int t = threadIdx.x;
    int lane = t & 63, wv = t >> 6;
    int m16 = lane & 15, quad = lane >> 4;
    // ---- weight fragments into registers (coalesced b128 from prepped) ----
    const f16* wg = wp + g*9216;
    half8 af[2][9];
#pragma unroll
    for (int mt = 0; mt < 2; ++mt)
#pragma unroll
        for (int ks = 0; ks < 9; ++ks)
            af[mt][ks] = *(const half8*)(wg + (mt*16 + m16)*288 + ks*32 + quad*8);
    float bo[2][4];
#pragma unroll
    for (int mt = 0; mt < 2; ++mt)
#pragma unroll
        for (int r = 0; r < 4; ++r)
            bo[mt][r] = bias[g*32 + mt*16 + quad*4 + r];
    // ---- stage 6 input rows (h0-1 .. h0+4) ----
    for (int idx = t; idx < 3120; idx += 256) {
        int r = idx / 520; int rem = idx - r*520; int p = rem >> 2; int q = rem & 3;
        int hr = h0 + r - 1; int wg2 = w0 + p - 1;
        uint4 val = make_uint4(0,0,0,0);
        if ((unsigned)wg2 < 256u && (unsigned)hr < 128u)
            val = *(const uint4*)(in + ((size_t)((b*128 + hr)*256 + wg2))*128 + g*32 + q*8);
        *(uint4*)&Xl[(r*130 + p)*40 + q*8] = val;
    }
    __syncthreads();
    int px0 = wv*32 + m16;
#pragma unroll
    for (int rr = 0; rr < 4; ++rr) {
        f32x4 acc[2][2] = {};
#pragma unroll
        for (int ks = 0; ks < 9; ++ks) {
            int ky = ks / 3, kx = ks - ky*3;
            half8 bf0 = *(const half8*)&Xl[((rr + ky)*130 + px0 + kx)*40 + quad*8];
            half8 bf1 = *(const half8*)&Xl[((rr + ky)*130 + px0 + 16 + kx)*40 + quad*8];
            acc[0][0] = __builtin_amdgcn_mfma_f32_16x16x32_f16(af[0][ks], bf0, acc[0][0], 0, 0, 0);
            acc[0][1] = __builtin_amdgcn_mfma_f32_16x16x32_f16(af[0][ks], bf1, acc[0][1], 0, 0, 0);
            acc[1][0] = __builtin_amdgcn_mfma_f32_16x16x32_f16(af[1][ks], bf0, acc[1][0], 0, 0, 0);
            acc[1][1] = __builtin_amdgcn_mfma_f32_16x16x32_f16(af[1][ks], bf1, acc[1][1], 0, 0, 0);
        }
        int h = h0 + rr;
#pragma unroll
        for (int mt = 0; mt < 2; ++mt)
#pragma unroll
            for (int nt = 0; nt < 2; ++nt) {
                int px = w0 + wv*32 + nt*16 + m16;
                int oc = g*32 + mt*16 + quad*4;
                size_t off = ((size_t)((b*128 + h)*256 + px))*128 + oc;
                float rv4[4] = {0.f, 0.f, 0.f, 0.f};
                if (RES) {
                    union { f16 h[4]; uint2 v2; } rrd;
                    rrd.v2 = *(const uint2*)(res + off);
#pragma unroll
                    for (int r = 0; r < 4; ++r) rv4[r] = (float)rrd.h[r];
                }
                union { f16 h[4]; uint2 v2; } ov;
#pragma unroll
                for (int r = 0; r < 4; ++r) {
                    float y = acc[mt][nt][r] + bo[mt][r];
                    if (LEAKY) y = y > 0.f ? y : 0.1f*y;
                    if (RES) y += rv4[r];
                    ov.h[r] = (f16)y;
                }
                *(uint2*)(out + off) = ov.v2;
            }
    }
}

// ---------------------------------------------------------------------------
// K4: grouped 1x1 conv (128->64, groups=2) + row-mean subtraction, MFMA f16.
// grid NN (one block per (b,h) row); 256 thr = 4 waves; each wave 64 px.
// Two passes over the groups share one 37 KB X-tile (LDS total 47 KB).
// Fragment math mirrors k_catbn_m (verified layout).
// ---------------------------------------------------------------------------
__global__ __launch_bounds__(256, 2) void k_conv1x1m(
    const f16* __restrict__ in, const float* __restrict__ wgt,
    f16* __restrict__ outq)
{
    __shared__ f16 Xl[256][72];       // one group's 64 ic (+8 pad)
    __shared__ f16 Wl[64][72];        // all 64 oc, within-group ic
    __shared__ float partial[4][64];  // per-wave px-sums per oc
    __shared__ float meanS[64];
    int n = blockIdx.x; int t = threadIdx.x;
    int lane = t & 63, wv = t >> 6;
    int m16 = lane & 15, quad = lane >> 4;
    // stage weights (4096 f32 -> f16), packed pairs
    for (int p = t; p < 2048; p += 256) {
        int idx = p * 2; int o = idx >> 6, i = idx & 63;
        union { f16 h[2]; unsigned int u1; } pr;
        pr.h[0] = (f16)wgt[idx]; pr.h[1] = (f16)wgt[idx + 1];
        *(unsigned int*)&Wl[o][i] = pr.u1;
    }
    f32x4 acc[4][4] = {};             // [oc tile 0..3][px tile 0..3]
    const f16* rp = in + ((size_t)n*256 + t)*128;
    for (int g = 0; g < 2; ++g) {
        // stage this group's input channels: thread t = px t (128 B/thread)
#pragma unroll
        for (int i8 = 0; i8 < 8; ++i8)
            *(uint4*)&Xl[t][i8*8] = *(const uint4*)(rp + g*64 + i8*8);
        __syncthreads();              // also covers Wl staging on g==0
        half8 af[2][2], bf[4][2];
#pragma unroll
        for (int ml = 0; ml < 2; ++ml)
#pragma unroll
            for (int kk = 0; kk < 2; ++kk)
                af[ml][kk] = *(const half8*)&Wl[g*32 + ml*16 + m16][kk*32 + quad*8];
#pragma unroll
        for (int nt = 0; nt < 4; ++nt)
#pragma unroll
            for (int kk = 0; kk < 2; ++kk)
                bf[nt][kk] = *(const half8*)&Xl[wv*64 + nt*16 + m16][kk*32 + quad*8];
#pragma unroll
        for (int ml = 0; ml < 2; ++ml)
#pragma unroll
            for (int nt = 0; nt < 4; ++nt) {
                int mt = g*2 + ml;
                acc[mt][nt] = __builtin_amdgcn_mfma_f32_16x16x32_f16(af[ml][0], bf[nt][0], acc[mt][nt], 0, 0, 0);
                acc[mt][nt] = __builtin_amdgcn_mfma_f32_16x16x32_f16(af[ml][1], bf[nt][1], acc[mt][nt], 0, 0, 0);
            }
        __syncthreads();              // Xl reused next pass
    }
    // ---- fused row-mean over the 256 px, per oc ----
#pragma unroll
    for (int mt = 0; mt < 4; ++mt)
#pragma unroll
        for (int r = 0; r < 4; ++r) {
            float s = acc[mt][0][r] + acc[mt][1][r] + acc[mt][2][r] + acc[mt][3][r];
            s += __shfl_xor(s, 1); s += __shfl_xor(s, 2);
            s += __shfl_xor(s, 4); s += __shfl_xor(s, 8);
            if (m16 == 0) partial[wv][mt*16 + quad*4 + r] = s;
        }
    __syncthreads();
    if (t < 64)
        meanS[t] = (partial[0][t] + partial[1][t] + partial[2][t] + partial[3][t]) * (1.0f/256.0f);
    __syncthreads();
    f16* qp = outq + ((size_t)n*256)*64;
#pragma unroll
    for (int mt = 0; mt < 4; ++mt) {
        int ocb = mt*16 + quad*4;
        float m4[4]; *(float4*)m4 = *(const float4*)&meanS[ocb];
#pragma unroll
        for (int nt = 0; nt < 4; ++nt) {
            int px = wv*64 + nt*16 + m16;
            union { f16 h[4]; uint2 u2; } ov;
#pragma unroll
            for (int r = 0; r < 4; ++r)
                ov.h[r] = (f16)(acc[mt][nt][r] - m4[r]);
            *(uint2*)(qp + (size_t)px*64 + ocb) = ov.u2;
        }
    }
}

// ---------------------------------------------------------------------------
// K5: score S = Q K^T per n via MFMA f16.  Writes S and ST (f16).
// ---------------------------------------------------------------------------
__global__ __launch_bounds__(256) void k_score(
    const f16* __restrict__ Q, const f16* __restrict__ K,
    f16* __restrict__ S, f16* __restrict__ ST)
{
    __shared__ f16 Qs[256][72];
    __shared__ f16 Ks[64][72];
    int n = blockIdx.x; int t = threadIdx.x;
    const f16* qg = Q + (size_t)n*16384 + (size_t)t*64;
#pragma unroll
    for (int k = 0; k < 8; ++k)
        *(uint4*)&Qs[t][k*8] = *(const uint4*)(qg + k*8);
    int lane = t & 63, wv = t >> 6;
    int m16 = lane & 15, quad = lane >> 4;
    int m0 = wv*64;
    half8 af[4][2];
    bool afl = false;
    f16* Sn = S + (size_t)n*65536;
    f16* STn = ST + (size_t)n*65536;
    for (int jc = 0; jc < 256; jc += 64) {
        __syncthreads();
        {
            int jj = t >> 2, seg = (t & 3) * 16;
            const f16* kg = K + (size_t)n*16384 + (size_t)(jc + jj)*64 + seg;
            *(uint4*)&Ks[jj][seg]     = *(const uint4*)(kg);
            *(uint4*)&Ks[jj][seg + 8] = *(const uint4*)(kg + 8);
        }
        __syncthreads();
        if (!afl) {
            afl = true;
#pragma unroll
            for (int mt = 0; mt < 4; ++mt)
#pragma unroll
                for (int kk = 0; kk < 2; ++kk)
                    af[mt][kk] = *(const half8*)&Qs[m0 + mt*16 + m16][kk*32 + quad*8];
        }
        half8 bf[4][2];
#pragma unroll
        for (int nt = 0; nt < 4; ++nt)
#pragma unroll
            for (int kk = 0; kk < 2; ++kk)
                bf[nt][kk] = *(const half8*)&Ks[nt*16 + m16][kk*32 + quad*8];
        f32x4 acc[4][4] = {};
#pragma unroll
        for (int mt = 0; mt < 4; ++mt)
#pragma unroll
            for (int nt = 0; nt < 4; ++nt) {
                acc[mt][nt] = __builtin_amdgcn_mfma_f32_16x16x32_f16(af[mt][0], bf[nt][0], acc[mt][nt], 0, 0, 0);
                acc[mt][nt] = __builtin_amdgcn_mfma_f32_16x16x32_f16(af[mt][1], bf[nt][1], acc[mt][nt], 0, 0, 0);
            }
#pragma unroll
        for (int mt = 0; mt < 4; ++mt)
#pragma unroll
            for (int nt = 0; nt < 4; ++nt) {
                int i = m0 + mt*16 + quad*4;
                int j = jc + nt*16 + m16;
                union { f16 h[4]; uint2 u2; } pv;
#pragma unroll
                for (int r = 0; r < 4; ++r) {
                    f16 vv = (f16)acc[mt][nt][r];
                    Sn[(size_t)(i + r)*256 + j] = vv;
                    pv.h[r] = vv;
                }
                *(uint2*)&STn[(size_t)j*256 + i] = pv.u2;
            }
    }
}

// ---------------------------------------------------------------------------
// K6: softmax stats, vectorized tile reads.  grid 512 (one block per n).
// ---------------------------------------------------------------------------
__global__ __launch_bounds__(256) void k_stats(
    const f16* __restrict__ S, float* __restrict__ rmax, float* __restrict__ rsumi,
    float* __restrict__ cmax, float* __restrict__ csumi)
{
    __shared__ float CM[8][260], CS[8][260];
    int n = blockIdx.x, t = threadIdx.x;
    int rphase = t >> 5;          // 0..7
    int c0 = (t & 31) * 8;
    const f16* Sp = S + (size_t)n*65536;
    float colm[8], cols[8];
#pragma unroll
    for (int e = 0; e < 8; ++e) { colm[e] = -1e30f; cols[e] = 0.f; }
    for (int g = 0; g < 32; ++g) {
        int row = g*8 + rphase;
        union { uint4 v4; f16 h[8]; } ld;
        ld.v4 = *(const uint4*)(Sp + (size_t)row*256 + c0);
        float v[8];
#pragma unroll
        for (int e = 0; e < 8; ++e) v[e] = (float)ld.h[e];
        float mx = v[0];
#pragma unroll
        for (int e = 1; e < 8; ++e) mx = fmaxf(mx, v[e]);
#pragma unroll
        for (int off = 1; off < 32; off <<= 1) mx = fmaxf(mx, __shfl_xor(mx, off));
        float es = 0.f;
#pragma unroll
        for (int e = 0; e < 8; ++e) es += __expf(v[e] - mx);
#pragma unroll
        for (int off = 1; off < 32; off <<= 1) es += __shfl_xor(es, off);
        if ((t & 31) == 0) { rmax[n*256 + row] = mx; rsumi[n*256 + row] = 1.0f/es; }
#pragma unroll
        for (int e = 0; e < 8; ++e) {
            float nm = fmaxf(colm[e], v[e]);
            cols[e] = cols[e]*__expf(colm[e] - nm) + __expf(v[e] - nm);
            colm[e] = nm;
        }
    }
#pragma unroll
    for (int e = 0; e < 8; ++e) { CM[rphase][c0 + e] = colm[e]; CS[rphase][c0 + e] = cols[e]; }
    __syncthreads();
    float m = CM[0][t], s = CS[0][t];
#pragma unroll
    for (int gp = 1; gp < 8; ++gp) {
        float m2 = CM[gp][t], s2 = CS[gp][t];
        float nm = fmaxf(m, m2);
        s = s*__expf(m - nm) + s2*__expf(m2 - nm);
        m = nm;
    }
    cmax[n*256 + t] = m;
    csumi[n*256 + t] = 1.0f/s;
}

// ---------------------------------------------------------------------------
// K8: out = xP*(1-tv) + (P @ xB)*tv,  tv = tanh(5 V), V fused in-kernel.
// ---------------------------------------------------------------------------
__global__ __launch_bounds__(256) void k_out(
    const f16* __restrict__ P16, const float* __restrict__ sm, const float* __restrict__ si,
    const float* __restrict__ om, const float* __restrict__ oi,
    const float* __restrict__ xB, const float* __restrict__ xP,
    float* __restrict__ outp)
{
    __shared__ f16 Pl[260][72];   // rows offset +2; rows 0,1,258,259 stay zero
    __shared__ f16 Xl[64][72];
    __shared__ float cmS[256], ciS[256];
    __shared__ float Vs[256];
    int n = blockIdx.x; int b = n >> 7; int h = n & 127;
    int t = threadIdx.x;
    int lane = t & 63, wv = t >> 6;
    int m16 = lane & 15, quad = lane >> 4;
    if (t < 18)      *(uint4*)(&Pl[0][0]   + t*8)      = make_uint4(0,0,0,0);
    else if (t < 36) *(uint4*)(&Pl[258][0] + (t-18)*8) = make_uint4(0,0,0,0);
    cmS[t] = om[n*256 + t];
    ciS[t] = oi[n*256 + t];
    float rm = sm[n*256 + t], ri = si[n*256 + t];
    f32x4 acc[4][4] = {};
    float vacc = 0.f;
    for (int kc = 0; kc < 256; kc += 64) {
        uint4 raw8[8];
        const f16* pg = P16 + (size_t)n*65536 + (size_t)t*256 + kc;
#pragma unroll
        for (int k8 = 0; k8 < 8; ++k8) {
            union { uint4 v4; f16 h[8]; } ldu, stu;
            ldu.v4 = *(const uint4*)(pg + k8*8);
            raw8[k8] = ldu.v4;
#pragma unroll
            for (int e = 0; e < 8; ++e)
                stu.h[e] = (f16)(__expf((float)ldu.h[e] - rm) * ri);
            *(uint4*)&Pl[t + 2][k8*8] = stu.v4;
        }
        {
            int c = t >> 2, j0 = (t & 3) * 16;
            const float* xg = xB + (((size_t)(b*64 + c)*128 + h) << 8) + kc + j0;
            union { uint4 v4; f16 h[8]; } xu0, xu1;
#pragma unroll
            for (int e = 0; e < 8; ++e) xu0.h[e] = (f16)xg[e];
#pragma unroll
            for (int e = 0; e < 8; ++e) xu1.h[e] = (f16)xg[8 + e];
            *(uint4*)&Xl[c][j0]     = xu0.v4;
            *(uint4*)&Xl[c][j0 + 8] = xu1.v4;
        }
        __syncthreads();
        int mbase = wv*64;
        half8 a0[4][2], b0[4][2];
#pragma unroll
        for (int mt = 0; mt < 4; ++mt)
#pragma unroll
            for (int kk = 0; kk < 2; ++kk)
                a0[mt][kk] = *(const half8*)&Pl[mbase + mt*16 + m16 + 2][kk*32 + quad*8];
#pragma unroll
        for (int nt = 0; nt < 4; ++nt)
#pragma unroll
            for (int kk = 0; kk < 2; ++kk)
                b0[nt][kk] = *(const half8*)&Xl[nt*16 + m16][kk*32 + quad*8];
#pragma unroll
        for (int mt = 0; mt < 4; ++mt)
#pragma unroll
            for (int nt = 0; nt < 4; ++nt) {
                acc[mt][nt] = __builtin_amdgcn_mfma_f32_16x16x32_f16(a0[mt][0], b0[nt][0], acc[mt][nt], 0, 0, 0);
                acc[mt][nt] = __builtin_amdgcn_mfma_f32_16x16x32_f16(a0[mt][1], b0[nt][1], acc[mt][nt], 0, 0, 0);
            }
#pragma unroll
        for (int j8 = 0; j8 < 8; ++j8) {
            int jl = j8*8;
            half8 w0 = *(const half8*)&Pl[t + 0][jl];
            half8 w1 = *(const half8*)&Pl[t + 1][jl];
            half8 w2 = *(const half8*)&Pl[t + 2][jl];
            half8 w3 = *(const half8*)&Pl[t + 3][jl];
            half8 w4 = *(const half8*)&Pl[t + 4][jl];
            half8 win = w0 + w1 + w2 + w3 + w4;
            union { uint4 v4; f16 h[8]; } rw; rw.v4 = raw8[j8];
#pragma unroll
            for (int e = 0; e < 8; ++e) {
                int j = kc + jl + e;
                float Bv = __expf((float)rw.h[e] - cmS[j]) * ciS[j];
                vacc = fmaf((float)win[e], Bv, vacc);
            }
        }
        __syncthreads();
    }
    Vs[t] = vacc;
    __syncthreads();
#pragma unroll
    for (int mt = 0; mt < 4; ++mt) {
        int i0 = wv*64 + mt*16 + quad*4;
        float v4[4];
        *(float4*)v4 = *(const float4*)&Vs[i0];
        float tv[4];
#pragma unroll
        for (int r = 0; r < 4; ++r) tv[r] = tanhf(5.f*v4[r]);
#pragma unroll
        for (int nt = 0; nt < 4; ++nt) {
            int c = nt*16 + m16;
            size_t base = (((size_t)(b*64 + c)*128 + h) << 8) + i0;
            float xp4[4]; *(float4*)xp4 = *(const float4*)&xP[base];
            float o4[4];
#pragma unroll
            for (int r = 0; r < 4; ++r)
                o4[r] = xp4[r]*(1.f - tv[r]) + acc[mt][nt][r]*tv[r];
            *(float4*)&outp[base] = *(float4*)o4;
        }
    }
}

// ---------------------------------------------------------------------------
extern "C" void kernel_launch(void* const* d_in, const int* in_sizes, int n_in,
                              void* d_out, int out_size, void* d_ws, size_t ws_size,
                              hipStream_t stream)
{
    const float* x_left  = (const float*)d_in[0];
    const float* x_right = (const float*)d_in[1];
    const float* conv1_w = (const float*)d_in[2];
    const float* conv1_b = (const float*)d_in[3];
    const float* conv2_w = (const float*)d_in[4];
    const float* conv2_b = (const float*)d_in[5];
    const float* bn_g    = (const float*)d_in[6];
    const float* bn_b    = (const float*)d_in[7];
    const float* bn_m    = (const float*)d_in[8];
    const float* bn_v    = (const float*)d_in[9];
    const float* rb_w1   = (const float*)d_in[10];
    const float* rb_b1   = (const float*)d_in[11];
    const float* rb_w2   = (const float*)d_in[12];
    const float* rb_b2   = (const float*)d_in[13];
    const float* bq_w    = (const float*)d_in[14];
    const float* bs_w    = (const float*)d_in[16];

    f16* W16 = (f16*)d_ws;
    f16* u  = W16;                       // 16,777,216 els
    f16* y1 = W16 + 16777216;            // 16,777,216
    f16* r  = W16 + 33554432;            // 16,777,216
    f16* S  = W16;                       // 33,554,432 (aliases u+y1)
    f16* ST = W16 + 33554432;            // 33,554,432 (aliases r + fresh)
    f16* Qh = W16 + 67108864;            //  8,388,608
    f16* Kh = W16 + 75497472;            //  8,388,608
    float* F32  = (float*)(W16 + 83886080);
    float* rmax  = F32;                  // 131,072
    float* rsumi = F32 + 131072;
    float* cmax  = F32 + 262144;         // 131,072
    float* csumi = F32 + 393216;         // 131,072
    f16* Wp1 = W16 + 84934656;           // 36,864 els (prepped rb_w1)
    f16* Wp2 = W16 + 84971520;           // 36,864 els (prepped rb_w2)

    float* out_left  = (float*)d_out;
    float* out_right = (float*)d_out + 8388608;

    // ---- weight prep (once per launch) ----
    k_wprep<<<dim3(4, 2), 256, 0, stream>>>(rb_w1, rb_w2, Wp1, Wp2);

    // ---- left branch -> Q ----
    k_catbn_m<<<NN, 256, 0, stream>>>(x_left, conv1_w, conv1_b, bn_g, bn_b, bn_m, bn_v, u);
    k_conv3r<true,  false><<<dim3(128, 4, 2), 256, 0, stream>>>(u, Wp1, rb_b1, nullptr, y1);
    k_conv3r<false, true ><<<dim3(128, 4, 2), 256, 0, stream>>>(y1, Wp2, rb_b2, u, r);
    k_conv1x1m<<<NN, 256, 0, stream>>>(r, bq_w, Qh);

    // ---- right branch -> K ----
    k_catbn_m<<<NN, 256, 0, stream>>>(x_right, conv2_w, conv2_b, bn_g, bn_b, bn_m, bn_v, u);
    k_conv3r<true,  false><<<dim3(128, 4, 2), 256, 0, stream>>>(u, Wp1, rb_b1, nullptr, y1);
    k_conv3r<false, true ><<<dim3(128, 4, 2), 256, 0, stream>>>(y1, Wp2, rb_b2, u, r);
    k_conv1x1m<<<NN, 256, 0, stream>>>(r, bs_w, Kh);

    // ---- attention ----
    k_score<<<NN, 256, 0, stream>>>(Qh, Kh, S, ST);
    k_stats<<<NN, 256, 0, stream>>>(S, rmax, rsumi, cmax, csumi);
    k_out<<<NN, 256, 0, stream>>>(S,  rmax, rsumi, cmax, csumi, x_right, x_left,  out_left);
    k_out<<<NN, 256, 0, stream>>>(ST, cmax, csumi, rmax, rsumi, x_left,  x_right, out_right);
}